// Round 11
// baseline (47.385 us; speedup 1.0000x reference)
//
#include <hip/hip_runtime.h>

// SHToGridDensity: density[row][g] = sum_{lm,r} coeffs[row][lm][r]*Y[lm][g]*R[r][g]
// row in 0..255, g in 0..35936. Inputs f32; OUTPUT f32 (verified r9).
//
// GEMM: D[256][G] = A[256][K=400(pad 416)] x B[416][G] on mfma_f32_16x16x32_bf16,
// B generated in-register from Y,R (RNE bf16, bit-identical to the r9-verified
// pipeline). r11 restructure: wave = 1 n-tile x ALL 16 m-tiles:
//   - B-gen computed once per g-column per block (was 2x)
//   - all 4 waves read identical A addresses in lockstep -> L1 absorbs sharing
//   - v_cvt_pk_bf16_f32 (1 instr) replaces manual RNE+pack (~11 instr)
//
// pack_coeffs fragment (mt,kc,lane): element j = coeffs[m=mt*16+(lane&15)]
//                                          [lm=lmFlat[2*kc+(h>>1)]][r=(h&1)*8+j]
// k-map k=h*8+j used identically by the B generator (A/B operand symmetry).
// D layout: col = lane&15 (g), row = (lane>>4)*4 + reg  (m89; r9-verified e2e).

#define G_TOTAL 35937
#define N_ROWS  256
#define KC_COUNT 13

typedef __attribute__((ext_vector_type(8))) short bf16x8;
typedef __attribute__((ext_vector_type(4))) float f32x4;

__device__ __forceinline__ unsigned short f32_bf16_rne(float f) {
    unsigned u = __float_as_uint(f);
    u += 0x7FFFu + ((u >> 16) & 1u);
    return (unsigned short)(u >> 16);
}

__constant__ int c_lmFlat[25] = {4, 12,13,14, 20,21,22,23,24,
                                 28,29,30,31,32,33,34,
                                 36,37,38,39,40,41,42,43,44};

__global__ void pack_coeffs(const float* __restrict__ coeffs,
                            unsigned short* __restrict__ packedA) {
    int t = blockIdx.x * 256 + threadIdx.x;      // exact grid: 16*13*64 = 13312
    if (t >= 16 * KC_COUNT * 64) return;
    int lane = t & 63;
    int mtkc = t >> 6;            // kc*16 + mt
    int mt = mtkc & 15;
    int kc = mtkc >> 4;
    int m  = mt * 16 + (lane & 15);
    int h  = lane >> 4;
    int lmIdx = 2 * kc + (h >> 1);

    uint4 v = make_uint4(0u, 0u, 0u, 0u);
    if (lmIdx < 25) {
        int base = m * 720 + c_lmFlat[lmIdx] * 16 + (h & 1) * 8;
        unsigned w[4];
#pragma unroll
        for (int p = 0; p < 4; ++p) {
            unsigned short lo = f32_bf16_rne(coeffs[base + 2 * p]);
            unsigned short hi = f32_bf16_rne(coeffs[base + 2 * p + 1]);
            w[p] = (unsigned)lo | ((unsigned)hi << 16);
        }
        v = make_uint4(w[0], w[1], w[2], w[3]);
    }
    ((uint4*)packedA)[t] = v;
}

// Main GEMM. 4 waves; wave w owns n-tile (blockIdx*4 + w) and ALL 16 m-tiles.
// grid = ceil(2247/4) = 562.
__global__ __launch_bounds__(256, 2) void sh_density(
        const unsigned short* __restrict__ packedA,
        const float* __restrict__ Y,
        const float* __restrict__ Rb,
        float* __restrict__ out) {
    const int l   = threadIdx.x & 63;
    const int w   = threadIdx.x >> 6;   // n-tile selector, 0..3
    const int h   = l >> 4;             // 0..3
    const int col = l & 15;

    const int gA  = (blockIdx.x * 4 + w) * 16 + col;
    const int gAc = gA < G_TOTAL ? gA : G_TOTAL - 1;
    const bool hOdd = (h & 1);
    const bool hHi  = (h >> 1);

    constexpr int lmFlat[25] = {4, 12,13,14, 20,21,22,23,24,
                                28,29,30,31,32,33,34,
                                36,37,38,39,40,41,42,43,44};

    // per-lane Y (26: slot 25 = 0 covers the K-pad) and pre-selected R
    float YA[26];
#pragma unroll
    for (int i = 0; i < 25; ++i) YA[i] = Y[lmFlat[i] * G_TOTAL + gAc];
    YA[25] = 0.0f;

    float RA[8];
#pragma unroll
    for (int j = 0; j < 8; ++j) {
        float a0 = Rb[j * G_TOTAL + gAc];
        float a1 = Rb[(8 + j) * G_TOTAL + gAc];
        RA[j] = hOdd ? a1 : a0;
    }

    f32x4 acc[16];
#pragma unroll
    for (int i = 0; i < 16; ++i) acc[i] = (f32x4){0.0f, 0.0f, 0.0f, 0.0f};

    const bf16x8* __restrict__ Ap = (const bf16x8*)packedA;

#pragma unroll
    for (int kc = 0; kc < KC_COUNT; ++kc) {
        const float y = hHi ? YA[2 * kc + 1] : YA[2 * kc];
        union { unsigned int u[4]; bf16x8 v; } fb;
#pragma unroll
        for (int p = 0; p < 4; ++p) {
            float lo = y * RA[2 * p];
            float hi = y * RA[2 * p + 1];
            unsigned r;
            asm("v_cvt_pk_bf16_f32 %0, %1, %2" : "=v"(r) : "v"(lo), "v"(hi));
            fb.u[p] = r;   // elem 2p in [15:0], 2p+1 in [31:16] == pack_coeffs order
        }
#pragma unroll
        for (int mt = 0; mt < 16; ++mt) {
            bf16x8 a = Ap[(kc * 16 + mt) * 64 + l];
            acc[mt] = __builtin_amdgcn_mfma_f32_16x16x32_bf16(a, fb.v, acc[mt], 0, 0, 0);
        }
    }

    // epilogue: lane l, reg q -> row = mt*16 + h*4 + q, col gA
    if (gA < G_TOTAL) {
        const int rowq = h * 4;
#pragma unroll
        for (int mt = 0; mt < 16; ++mt) {
            const int rowbase = mt * 16 + rowq;
#pragma unroll
            for (int q = 0; q < 4; ++q)
                out[(rowbase + q) * G_TOTAL + gA] = acc[mt][q];
        }
    }
}

extern "C" void kernel_launch(void* const* d_in, const int* in_sizes, int n_in,
                              void* d_out, int out_size, void* d_ws, size_t ws_size,
                              hipStream_t stream) {
    // pointer identification by element count (robust to dict-order changes)
    const float *pC = nullptr, *pY = nullptr, *pR = nullptr;
    if (n_in >= 3) {
        for (int i = 0; i < 3; ++i) {
            if      (in_sizes[i] == 256 * 720)    pC = (const float*)d_in[i];
            else if (in_sizes[i] == 45 * G_TOTAL) pY = (const float*)d_in[i];
            else if (in_sizes[i] == 16 * G_TOTAL) pR = (const float*)d_in[i];
        }
    }
    if (!pC || !pY || !pR) {
        pC = (const float*)d_in[0];
        pY = (const float*)d_in[1];
        pR = (const float*)d_in[2];
    }

    float* out = (float*)d_out;                       // f32 output (r9-verified)
    unsigned short* packedA = (unsigned short*)d_ws;  // 212992 B

    pack_coeffs<<<52, 256, 0, stream>>>(pC, packedA);
    sh_density<<<562, 256, 0, stream>>>(packedA, pY, pR, out);

    (void)out_size; (void)n_in; (void)ws_size;
}